// Round 5
// baseline (310.301 us; speedup 1.0000x reference)
//
#include <hip/hip_runtime.h>
#include <hip/hip_bf16.h>

typedef _Float16 half4v __attribute__((ext_vector_type(4)));
typedef _Float16 half8v __attribute__((ext_vector_type(8)));
typedef float float4v __attribute__((ext_vector_type(4)));

#define L_SEQ 2048
#define EMB 1024
#define NH 16
#define DKV 64

__device__ inline void gll16(const void* g, void* l) {
  __builtin_amdgcn_global_load_lds((const __attribute__((address_space(1))) void*)g,
                                   (__attribute__((address_space(3))) void*)l, 16, 0, 0);
}

// ---------------------------------------------------------------------------
// Kernel A: cast X fp32 -> f16 (4096x1024), 8 elems/thread
// ---------------------------------------------------------------------------
__global__ __launch_bounds__(256) void xcast_kernel(const float* __restrict__ X,
                                                    _Float16* __restrict__ X16) {
  size_t i = ((size_t)blockIdx.x * 256 + threadIdx.x) * 8;
  float4v v0 = *(const float4v*)(X + i);
  float4v v1 = *(const float4v*)(X + i + 4);
  half8v h;
  h[0] = (_Float16)v0[0]; h[1] = (_Float16)v0[1]; h[2] = (_Float16)v0[2]; h[3] = (_Float16)v0[3];
  h[4] = (_Float16)v1[0]; h[5] = (_Float16)v1[1]; h[6] = (_Float16)v1[2]; h[7] = (_Float16)v1[3];
  *(half8v*)(X16 + i) = h;
}

// ---------------------------------------------------------------------------
// Kernel B: pack + transpose + cast W_qkv (fp32 [1024][3072]) -> Wt (f16 [2048][1024])
// ---------------------------------------------------------------------------
__global__ __launch_bounds__(256) void wpack_kernel(const float* __restrict__ W,
                                                    _Float16* __restrict__ Wt) {
  __shared__ float tile[32][33];
  int n0 = blockIdx.x * 32;
  int k0 = blockIdx.y * 32;
  int h = n0 >> 7;
  int wc = h * 192 + (n0 & 127);
  int tx = threadIdx.x & 31;
  int ty = threadIdx.x >> 5;
#pragma unroll
  for (int i = 0; i < 4; ++i) {
    int k = ty + i * 8;
    tile[k][tx] = W[(size_t)(k0 + k) * 3072 + wc + tx];
  }
  __syncthreads();
#pragma unroll
  for (int i = 0; i < 4; ++i) {
    int n = ty + i * 8;
    Wt[(size_t)(n0 + n) * 1024 + k0 + tx] = (_Float16)tile[tx][n];
  }
}

// ---------------------------------------------------------------------------
// Kernel C: Q/K projection GEMM (m97 structure). unchanged
// ---------------------------------------------------------------------------
__global__ __launch_bounds__(256) void qk_gemm_kernel(const _Float16* __restrict__ X16,
                                                      const _Float16* __restrict__ Wt,
                                                      const float* __restrict__ bias,
                                                      _Float16* __restrict__ Qh,
                                                      _Float16* __restrict__ Kh) {
  __shared__ _Float16 As[128 * 32];
  __shared__ _Float16 Bs[128 * 32];
  int n0 = blockIdx.x * 128;
  int m0 = blockIdx.y * 128;
  int t = threadIdx.x;
  int l = t & 63;
  int wv = t >> 6;
  int wm = wv >> 1, wn = wv & 1;
  int cl = l & 15, ko = (l >> 4) * 8;
  int srow = (l >> 2);
  int scol = (l & 3) * 8;
  float4v acc[4][4] = {};
  for (int k0 = 0; k0 < 1024; k0 += 32) {
#pragma unroll
    for (int c = 0; c < 2; ++c) {
      int rbase = wv * 32 + c * 16;
      gll16(X16 + (size_t)(m0 + rbase + srow) * 1024 + k0 + scol, &As[rbase * 32]);
      gll16(Wt + (size_t)(n0 + rbase + srow) * 1024 + k0 + scol, &Bs[rbase * 32]);
    }
    __syncthreads();
    half8v a[4], b[4];
#pragma unroll
    for (int mt = 0; mt < 4; ++mt) a[mt] = *(const half8v*)(&As[(wm * 64 + mt * 16 + cl) * 32 + ko]);
#pragma unroll
    for (int nt = 0; nt < 4; ++nt) b[nt] = *(const half8v*)(&Bs[(wn * 64 + nt * 16 + cl) * 32 + ko]);
#pragma unroll
    for (int mt = 0; mt < 4; ++mt)
#pragma unroll
      for (int nt = 0; nt < 4; ++nt)
        acc[mt][nt] = __builtin_amdgcn_mfma_f32_16x16x32_f16(a[mt], b[nt], acc[mt][nt], 0, 0, 0);
    __syncthreads();
  }
#pragma unroll
  for (int mt = 0; mt < 4; ++mt) {
#pragma unroll
    for (int nt = 0; nt < 4; ++nt) {
      int n_g = n0 + wn * 64 + nt * 16 + cl;
      int hh = n_g >> 7, rr = n_g & 127;
      float bv = bias[hh * 192 + rr];
      _Float16* dstbase = (rr < 64) ? Qh : Kh;
      int d = rr & 63;
#pragma unroll
      for (int r = 0; r < 4; ++r) {
        int row_g = m0 + wm * 64 + mt * 16 + (l >> 4) * 4 + r;
        int bb = row_g >> 11, lr = row_g & 2047;
        dstbase[(((size_t)bb * NH + hh) * L_SEQ + lr) * DKV + d] = (_Float16)(acc[mt][nt][r] + bv);
      }
    }
  }
}

// ---------------------------------------------------------------------------
// Kernel D (v5): S = Q K^T / 8, softmax over j, write [B][H][L][L] fp32.
// j-split waves: wave wv owns j-rows [jt*64+wv*16, +16) for ALL 64 q of the
// block. Q (64q x 64d) lives in registers (8 half8v). K fragments are per-lane
// global loads (L2-resident panel, XCD-swizzled), register-double-buffered one
// tile ahead. No LDS staging, no transposes, barrier only for the cross-wave
// sum reduction. MFMA(A=K, B=Q): lane holds 4 consecutive j for one q ->
// direct float4 stores; the block's 4 waves jointly fill each 256-B line.
// ---------------------------------------------------------------------------
__global__ __launch_bounds__(256, 4) void attn_softmax_kernel(const _Float16* __restrict__ Qh,
                                                              const _Float16* __restrict__ Kh,
                                                              float* __restrict__ out) {
  __shared__ float sums[4][4][16];  // [wave][qgroup][cl]
  int id = blockIdx.x;
  int xcd = id & 7;
  int rest = id >> 3;
  int rb = rest & 31;
  int bh = ((rest >> 5) << 3) + xcd;  // bijective XCD swizzle: same-bh -> same XCD
  int t = threadIdx.x;
  int l = t & 63;
  int wv = t >> 6;
  int cl = l & 15;   // 16-index: q within group (B operand) / j within slice (A operand)
  int hi = l >> 4;   // k-chunk
  int qbase = rb * 64;
  const _Float16* Qb = Qh + ((size_t)bh * L_SEQ + qbase) * DKV;
  // per-lane K fragment base: row = wv*16 + cl, k-offset hi*8
  const _Float16* Kf = Kh + (size_t)bh * L_SEQ * DKV + (size_t)(wv * 16 + cl) * DKV + hi * 8;
  const float SC = 0.18033688011112042f;  // log2(e)/sqrt(64)

  // Q fragments: bq[g][dh] = Q[qbase + g*16 + cl][dh*32 + hi*8 ..]
  half8v bq[4][2];
#pragma unroll
  for (int g = 0; g < 4; ++g)
#pragma unroll
    for (int dh = 0; dh < 2; ++dh)
      bq[g][dh] = *(const half8v*)(Qb + (size_t)(g * 16 + cl) * DKV + dh * 32 + hi * 8);

  // ---- Pass 1: row sums (register-dbuf K prefetch, no barriers) ----
  float lsum[4] = {0.f, 0.f, 0.f, 0.f};
  half8v k0c = *(const half8v*)(Kf);
  half8v k1c = *(const half8v*)(Kf + 32);
  for (int jt = 0; jt < 32; ++jt) {
    int jn = (jt + 1) & 31;  // branchless wrap: last iter re-reads tile 0 (in-bounds)
    half8v k0n = *(const half8v*)(Kf + (size_t)jn * 64 * DKV);
    half8v k1n = *(const half8v*)(Kf + (size_t)jn * 64 * DKV + 32);
#pragma unroll
    for (int g = 0; g < 4; ++g) {
      float4v acc = {};
      acc = __builtin_amdgcn_mfma_f32_16x16x32_f16(k0c, bq[g][0], acc, 0, 0, 0);
      acc = __builtin_amdgcn_mfma_f32_16x16x32_f16(k1c, bq[g][1], acc, 0, 0, 0);
      lsum[g] += __builtin_amdgcn_exp2f(acc[0] * SC) + __builtin_amdgcn_exp2f(acc[1] * SC) +
                 __builtin_amdgcn_exp2f(acc[2] * SC) + __builtin_amdgcn_exp2f(acc[3] * SC);
    }
    k0c = k0n;
    k1c = k1n;
  }
  // reduce over hi within wave (lanes sharing cl): xor 16, 32
#pragma unroll
  for (int g = 0; g < 4; ++g) {
    lsum[g] += __shfl_xor(lsum[g], 16);
    lsum[g] += __shfl_xor(lsum[g], 32);
  }
  if (hi == 0) {
#pragma unroll
    for (int g = 0; g < 4; ++g) sums[wv][g][cl] = lsum[g];
  }
  __syncthreads();
  float inv[4];
#pragma unroll
  for (int g = 0; g < 4; ++g)
    inv[g] = 1.0f / (sums[0][g][cl] + sums[1][g][cl] + sums[2][g][cl] + sums[3][g][cl]);

  // ---- Pass 2: recompute, normalize, direct float4 stores ----
  // store addr for (g, lane): row q = qbase + g*16 + cl, col = jt*64 + wv*16 + hi*4
  float* ob[4];
#pragma unroll
  for (int g = 0; g < 4; ++g)
    ob[g] = out + ((size_t)bh * L_SEQ + qbase + g * 16 + cl) * L_SEQ + wv * 16 + hi * 4;
  k0c = *(const half8v*)(Kf);
  k1c = *(const half8v*)(Kf + 32);
  for (int jt = 0; jt < 32; ++jt) {
    int jn = (jt + 1) & 31;
    half8v k0n = *(const half8v*)(Kf + (size_t)jn * 64 * DKV);
    half8v k1n = *(const half8v*)(Kf + (size_t)jn * 64 * DKV + 32);
#pragma unroll
    for (int g = 0; g < 4; ++g) {
      float4v acc = {};
      acc = __builtin_amdgcn_mfma_f32_16x16x32_f16(k0c, bq[g][0], acc, 0, 0, 0);
      acc = __builtin_amdgcn_mfma_f32_16x16x32_f16(k1c, bq[g][1], acc, 0, 0, 0);
      float4v p;
      p[0] = __builtin_amdgcn_exp2f(acc[0] * SC) * inv[g];
      p[1] = __builtin_amdgcn_exp2f(acc[1] * SC) * inv[g];
      p[2] = __builtin_amdgcn_exp2f(acc[2] * SC) * inv[g];
      p[3] = __builtin_amdgcn_exp2f(acc[3] * SC) * inv[g];
      *(float4v*)(ob[g] + jt * 64) = p;
    }
    k0c = k0n;
    k1c = k1n;
  }
}

// ---------------------------------------------------------------------------
extern "C" void kernel_launch(void* const* d_in, const int* in_sizes, int n_in,
                              void* d_out, int out_size, void* d_ws, size_t ws_size,
                              hipStream_t stream) {
  const float* X = (const float*)d_in[0];
  const float* W = (const float*)d_in[1];
  const float* bias = (const float*)d_in[2];
  float* out = (float*)d_out;
  char* ws = (char*)d_ws;
  _Float16* Wt = (_Float16*)ws;                       // 4 MB
  _Float16* Qh = (_Float16*)(ws + (4ull << 20));      // 8 MB
  _Float16* Kh = (_Float16*)(ws + (12ull << 20));     // 8 MB
  _Float16* X16 = (_Float16*)(ws + (20ull << 20));    // 8 MB (total 28 MB)

  xcast_kernel<<<2048, 256, 0, stream>>>(X, X16);
  wpack_kernel<<<dim3(64, 32), 256, 0, stream>>>(W, Wt);
  qk_gemm_kernel<<<dim3(16, 32), 256, 0, stream>>>(X16, Wt, bias, Qh, Kh);
  attn_softmax_kernel<<<1024, 256, 0, stream>>>(Qh, Kh, out);
}

// Round 6
// 162.764 us; speedup vs baseline: 1.9065x; 1.9065x over previous
//
#include <hip/hip_runtime.h>
#include <hip/hip_bf16.h>

typedef _Float16 half4v __attribute__((ext_vector_type(4)));
typedef _Float16 half8v __attribute__((ext_vector_type(8)));
typedef float float4v __attribute__((ext_vector_type(4)));
typedef float float16v __attribute__((ext_vector_type(16)));

#define L_SEQ 2048
#define EMB 1024
#define NH 16
#define DKV 64

__device__ inline void gll16(const void* g, void* l) {
  __builtin_amdgcn_global_load_lds((const __attribute__((address_space(1))) void*)g,
                                   (__attribute__((address_space(3))) void*)l, 16, 0, 0);
}

// ---------------------------------------------------------------------------
// Kernel A: cast X fp32 -> f16 (4096x1024), 8 elems/thread
// ---------------------------------------------------------------------------
__global__ __launch_bounds__(256) void xcast_kernel(const float* __restrict__ X,
                                                    _Float16* __restrict__ X16) {
  size_t i = ((size_t)blockIdx.x * 256 + threadIdx.x) * 8;
  float4v v0 = *(const float4v*)(X + i);
  float4v v1 = *(const float4v*)(X + i + 4);
  half8v h;
  h[0] = (_Float16)v0[0]; h[1] = (_Float16)v0[1]; h[2] = (_Float16)v0[2]; h[3] = (_Float16)v0[3];
  h[4] = (_Float16)v1[0]; h[5] = (_Float16)v1[1]; h[6] = (_Float16)v1[2]; h[7] = (_Float16)v1[3];
  *(half8v*)(X16 + i) = h;
}

// ---------------------------------------------------------------------------
// Kernel B: pack + transpose + cast W_qkv (fp32 [1024][3072]) -> Wt (f16 [2048][1024])
// ---------------------------------------------------------------------------
__global__ __launch_bounds__(256) void wpack_kernel(const float* __restrict__ W,
                                                    _Float16* __restrict__ Wt) {
  __shared__ float tile[32][33];
  int n0 = blockIdx.x * 32;
  int k0 = blockIdx.y * 32;
  int h = n0 >> 7;
  int wc = h * 192 + (n0 & 127);
  int tx = threadIdx.x & 31;
  int ty = threadIdx.x >> 5;
#pragma unroll
  for (int i = 0; i < 4; ++i) {
    int k = ty + i * 8;
    tile[k][tx] = W[(size_t)(k0 + k) * 3072 + wc + tx];
  }
  __syncthreads();
#pragma unroll
  for (int i = 0; i < 4; ++i) {
    int n = ty + i * 8;
    Wt[(size_t)(n0 + n) * 1024 + k0 + tx] = (_Float16)tile[tx][n];
  }
}

// ---------------------------------------------------------------------------
// Kernel C: Q/K projection GEMM (m97 structure). unchanged
// ---------------------------------------------------------------------------
__global__ __launch_bounds__(256) void qk_gemm_kernel(const _Float16* __restrict__ X16,
                                                      const _Float16* __restrict__ Wt,
                                                      const float* __restrict__ bias,
                                                      _Float16* __restrict__ Qh,
                                                      _Float16* __restrict__ Kh) {
  __shared__ _Float16 As[128 * 32];
  __shared__ _Float16 Bs[128 * 32];
  int n0 = blockIdx.x * 128;
  int m0 = blockIdx.y * 128;
  int t = threadIdx.x;
  int l = t & 63;
  int wv = t >> 6;
  int wm = wv >> 1, wn = wv & 1;
  int cl = l & 15, ko = (l >> 4) * 8;
  int srow = (l >> 2);
  int scol = (l & 3) * 8;
  float4v acc[4][4] = {};
  for (int k0 = 0; k0 < 1024; k0 += 32) {
#pragma unroll
    for (int c = 0; c < 2; ++c) {
      int rbase = wv * 32 + c * 16;
      gll16(X16 + (size_t)(m0 + rbase + srow) * 1024 + k0 + scol, &As[rbase * 32]);
      gll16(Wt + (size_t)(n0 + rbase + srow) * 1024 + k0 + scol, &Bs[rbase * 32]);
    }
    __syncthreads();
    half8v a[4], b[4];
#pragma unroll
    for (int mt = 0; mt < 4; ++mt) a[mt] = *(const half8v*)(&As[(wm * 64 + mt * 16 + cl) * 32 + ko]);
#pragma unroll
    for (int nt = 0; nt < 4; ++nt) b[nt] = *(const half8v*)(&Bs[(wn * 64 + nt * 16 + cl) * 32 + ko]);
#pragma unroll
    for (int mt = 0; mt < 4; ++mt)
#pragma unroll
      for (int nt = 0; nt < 4; ++nt)
        acc[mt][nt] = __builtin_amdgcn_mfma_f32_16x16x32_f16(a[mt], b[nt], acc[mt][nt], 0, 0, 0);
    __syncthreads();
  }
#pragma unroll
  for (int mt = 0; mt < 4; ++mt) {
#pragma unroll
    for (int nt = 0; nt < 4; ++nt) {
      int n_g = n0 + wn * 64 + nt * 16 + cl;
      int hh = n_g >> 7, rr = n_g & 127;
      float bv = bias[hh * 192 + rr];
      _Float16* dstbase = (rr < 64) ? Qh : Kh;
      int d = rr & 63;
#pragma unroll
      for (int r = 0; r < 4; ++r) {
        int row_g = m0 + wm * 64 + mt * 16 + (l >> 4) * 4 + r;
        int bb = row_g >> 11, lr = row_g & 2047;
        dstbase[(((size_t)bb * NH + hh) * L_SEQ + lr) * DKV + d] = (_Float16)(acc[mt][nt][r] + bv);
      }
    }
  }
}

// ---------------------------------------------------------------------------
// Kernel D (v6): S = Q K^T / 8, softmax over j, write [B][H][L][L] fp32.
// Round-4 LDS-staged base (global_load_lds dbuf, XOR-swizzled granules),
// upgraded: 32x32x16 MFMA; 128-j steps (half the barriers); dual-orientation
// passes sharing fragments -- pass1 mfma(K,Q): lane = q-col, in-lane row sums;
// pass2 mfma(Q,K): lane = j-col, regs = 16 q-rows -> direct 128B-line dword
// stores, no transpose. Normalization folded into exponent: exp2(s*SC - log2(sum)).
// Nontemporal stores keep the K panel L2-resident.
// ---------------------------------------------------------------------------
__global__ __launch_bounds__(256, 4) void attn_softmax_kernel(const _Float16* __restrict__ Qh,
                                                              const _Float16* __restrict__ Kh,
                                                              float* __restrict__ out) {
  __shared__ _Float16 Ks[2][128 * 64];  // 32 KB dbuf, granule-swizzled rows
  __shared__ float sums[4][32];
  int id = blockIdx.x;
  int xcd = id & 7;
  int rest = id >> 3;
  int rb = rest & 31;
  int bh = ((rest >> 5) << 3) + xcd;  // bijective XCD swizzle
  int t = threadIdx.x;
  int l = t & 63;
  int wv = t >> 6;
  int lj = l & 31;   // 32-lane index (q-col in pass1 / j-col in pass2)
  int hk = l >> 5;   // k-half
  int qh = wv & 1;   // q-half owned by this wave
  int jh = wv >> 1;  // j-half of each 128-step
  int qbase = rb * 64;
  const _Float16* Qb = Qh + ((size_t)bh * L_SEQ + qbase) * DKV;
  const _Float16* Kb = Kh + (size_t)bh * L_SEQ * DKV;
  const float SC = 0.18033688011112042f;  // log2(e)/sqrt(64)

  // Q fragments (shared by both MFMA orientations): index = qh*32+lj, k = ks*16 + hk*8
  half8v bq[4];
#pragma unroll
  for (int ks = 0; ks < 4; ++ks)
    bq[ks] = *(const half8v*)(Qb + (size_t)(qh * 32 + lj) * DKV + ks * 16 + hk * 8);

  // Stage one 128x64 f16 K tile; linear LDS dest, source granule s stored at
  // slot s^(row&7) so stride-128B fragment reads are spread across banks.
#define STAGE(bufi, j0)                                                     \
  {                                                                         \
    _Pragma("unroll") for (int c = 0; c < 4; ++c) {                         \
      int gi = (wv * 4 + c) * 64 + l;                                       \
      int r_ = gi >> 3, s_ = gi & 7;                                        \
      gll16(Kb + (size_t)((j0) + r_) * DKV + 8 * (s_ ^ (r_ & 7)),           \
            &Ks[bufi][(wv * 4 + c) * 512]);                                 \
    }                                                                       \
  }

  // ---- Pass 1: row sums.  mfma(A=K, B=Q): D col = q (lj), rows = j ----
  float lsum = 0.f;
  int buf = 0;
  STAGE(0, 0);
  __syncthreads();
  for (int s = 0; s < 16; ++s) {
    if (s + 1 < 16) STAGE(buf ^ 1, (s + 1) * 128);
#pragma unroll
    for (int q2 = 0; q2 < 2; ++q2) {
      int jq = jh * 2 + q2;
      int krow = jq * 32 + lj;
      half8v bk[4];
#pragma unroll
      for (int ks = 0; ks < 4; ++ks)
        bk[ks] = *(const half8v*)(&Ks[buf][krow * 64 + 8 * ((2 * ks + hk) ^ (krow & 7))]);
      float16v acc = {};
#pragma unroll
      for (int ks = 0; ks < 4; ++ks)
        acc = __builtin_amdgcn_mfma_f32_32x32x16_f16(bk[ks], bq[ks], acc, 0, 0, 0);
#pragma unroll
      for (int i = 0; i < 16; ++i) lsum += __builtin_amdgcn_exp2f(acc[i] * SC);
    }
    __syncthreads();
    buf ^= 1;
  }
  lsum += __shfl_xor(lsum, 32);
  if (l < 32) sums[wv][lj] = lsum;
  __syncthreads();

  // fold normalization into the exponent: c[i] = -log2(sum[q_i])
  float cc[16];
#pragma unroll
  for (int i = 0; i < 16; ++i) {
    int qo = (i & 3) + 8 * (i >> 2) + 4 * hk;  // q within the wave's 32-q half
    cc[i] = -__log2f(sums[qh][qo] + sums[qh + 2][qo]);
  }

  // ---- Pass 2: recompute, mfma(A=Q, B=K): D col = j (lj), rows = q ----
  size_t orow0 = ((size_t)bh * L_SEQ + qbase + qh * 32) * L_SEQ;
  STAGE(0, 0);
  __syncthreads();
  buf = 0;
  for (int s = 0; s < 16; ++s) {
    if (s + 1 < 16) STAGE(buf ^ 1, (s + 1) * 128);
#pragma unroll
    for (int q2 = 0; q2 < 2; ++q2) {
      int jq = jh * 2 + q2;
      int krow = jq * 32 + lj;
      half8v bk[4];
#pragma unroll
      for (int ks = 0; ks < 4; ++ks)
        bk[ks] = *(const half8v*)(&Ks[buf][krow * 64 + 8 * ((2 * ks + hk) ^ (krow & 7))]);
      float16v acc = {};
#pragma unroll
      for (int ks = 0; ks < 4; ++ks)
        acc = __builtin_amdgcn_mfma_f32_32x32x16_f16(bq[ks], bk[ks], acc, 0, 0, 0);
      size_t col = (size_t)s * 128 + jq * 32 + lj;
#pragma unroll
      for (int i = 0; i < 16; ++i) {
        float p = __builtin_amdgcn_exp2f(acc[i] * SC + cc[i]);
        int qo = (i & 3) + 8 * (i >> 2) + 4 * hk;
        __builtin_nontemporal_store(p, out + orow0 + (size_t)qo * L_SEQ + col);
      }
    }
    __syncthreads();
    buf ^= 1;
  }
#undef STAGE
}

// ---------------------------------------------------------------------------
extern "C" void kernel_launch(void* const* d_in, const int* in_sizes, int n_in,
                              void* d_out, int out_size, void* d_ws, size_t ws_size,
                              hipStream_t stream) {
  const float* X = (const float*)d_in[0];
  const float* W = (const float*)d_in[1];
  const float* bias = (const float*)d_in[2];
  float* out = (float*)d_out;
  char* ws = (char*)d_ws;
  _Float16* Wt = (_Float16*)ws;                       // 4 MB
  _Float16* Qh = (_Float16*)(ws + (4ull << 20));      // 8 MB
  _Float16* Kh = (_Float16*)(ws + (12ull << 20));     // 8 MB
  _Float16* X16 = (_Float16*)(ws + (20ull << 20));    // 8 MB (total 28 MB)

  xcast_kernel<<<2048, 256, 0, stream>>>(X, X16);
  wpack_kernel<<<dim3(64, 32), 256, 0, stream>>>(W, Wt);
  qk_gemm_kernel<<<dim3(16, 32), 256, 0, stream>>>(X16, Wt, bias, Qh, Kh);
  attn_softmax_kernel<<<1024, 256, 0, stream>>>(Qh, Kh, out);
}

// Round 7
// 161.567 us; speedup vs baseline: 1.9206x; 1.0074x over previous
//
#include <hip/hip_runtime.h>
#include <hip/hip_bf16.h>

typedef _Float16 half4v __attribute__((ext_vector_type(4)));
typedef _Float16 half8v __attribute__((ext_vector_type(8)));
typedef float float4v __attribute__((ext_vector_type(4)));
typedef float float16v __attribute__((ext_vector_type(16)));

#define L_SEQ 2048
#define EMB 1024
#define NH 16
#define DKV 64

__device__ inline void gll16(const void* g, void* l) {
  __builtin_amdgcn_global_load_lds((const __attribute__((address_space(1))) void*)g,
                                   (__attribute__((address_space(3))) void*)l, 16, 0, 0);
}

// ---------------------------------------------------------------------------
// Kernel A: cast X fp32 -> f16 (4096x1024), 8 elems/thread
// ---------------------------------------------------------------------------
__global__ __launch_bounds__(256) void xcast_kernel(const float* __restrict__ X,
                                                    _Float16* __restrict__ X16) {
  size_t i = ((size_t)blockIdx.x * 256 + threadIdx.x) * 8;
  float4v v0 = *(const float4v*)(X + i);
  float4v v1 = *(const float4v*)(X + i + 4);
  half8v h;
  h[0] = (_Float16)v0[0]; h[1] = (_Float16)v0[1]; h[2] = (_Float16)v0[2]; h[3] = (_Float16)v0[3];
  h[4] = (_Float16)v1[0]; h[5] = (_Float16)v1[1]; h[6] = (_Float16)v1[2]; h[7] = (_Float16)v1[3];
  *(half8v*)(X16 + i) = h;
}

// ---------------------------------------------------------------------------
// Kernel B: pack + transpose + cast W_qkv (fp32 [1024][3072]) -> Wt (f16 [2048][1024])
// ---------------------------------------------------------------------------
__global__ __launch_bounds__(256) void wpack_kernel(const float* __restrict__ W,
                                                    _Float16* __restrict__ Wt) {
  __shared__ float tile[32][33];
  int n0 = blockIdx.x * 32;
  int k0 = blockIdx.y * 32;
  int h = n0 >> 7;
  int wc = h * 192 + (n0 & 127);
  int tx = threadIdx.x & 31;
  int ty = threadIdx.x >> 5;
#pragma unroll
  for (int i = 0; i < 4; ++i) {
    int k = ty + i * 8;
    tile[k][tx] = W[(size_t)(k0 + k) * 3072 + wc + tx];
  }
  __syncthreads();
#pragma unroll
  for (int i = 0; i < 4; ++i) {
    int n = ty + i * 8;
    Wt[(size_t)(n0 + n) * 1024 + k0 + tx] = (_Float16)tile[tx][n];
  }
}

// ---------------------------------------------------------------------------
// Kernel C: Q/K projection GEMM (m97 structure). unchanged
// ---------------------------------------------------------------------------
__global__ __launch_bounds__(256) void qk_gemm_kernel(const _Float16* __restrict__ X16,
                                                      const _Float16* __restrict__ Wt,
                                                      const float* __restrict__ bias,
                                                      _Float16* __restrict__ Qh,
                                                      _Float16* __restrict__ Kh) {
  __shared__ _Float16 As[128 * 32];
  __shared__ _Float16 Bs[128 * 32];
  int n0 = blockIdx.x * 128;
  int m0 = blockIdx.y * 128;
  int t = threadIdx.x;
  int l = t & 63;
  int wv = t >> 6;
  int wm = wv >> 1, wn = wv & 1;
  int cl = l & 15, ko = (l >> 4) * 8;
  int srow = (l >> 2);
  int scol = (l & 3) * 8;
  float4v acc[4][4] = {};
  for (int k0 = 0; k0 < 1024; k0 += 32) {
#pragma unroll
    for (int c = 0; c < 2; ++c) {
      int rbase = wv * 32 + c * 16;
      gll16(X16 + (size_t)(m0 + rbase + srow) * 1024 + k0 + scol, &As[rbase * 32]);
      gll16(Wt + (size_t)(n0 + rbase + srow) * 1024 + k0 + scol, &Bs[rbase * 32]);
    }
    __syncthreads();
    half8v a[4], b[4];
#pragma unroll
    for (int mt = 0; mt < 4; ++mt) a[mt] = *(const half8v*)(&As[(wm * 64 + mt * 16 + cl) * 32 + ko]);
#pragma unroll
    for (int nt = 0; nt < 4; ++nt) b[nt] = *(const half8v*)(&Bs[(wn * 64 + nt * 16 + cl) * 32 + ko]);
#pragma unroll
    for (int mt = 0; mt < 4; ++mt)
#pragma unroll
      for (int nt = 0; nt < 4; ++nt)
        acc[mt][nt] = __builtin_amdgcn_mfma_f32_16x16x32_f16(a[mt], b[nt], acc[mt][nt], 0, 0, 0);
    __syncthreads();
  }
#pragma unroll
  for (int mt = 0; mt < 4; ++mt) {
#pragma unroll
    for (int nt = 0; nt < 4; ++nt) {
      int n_g = n0 + wn * 64 + nt * 16 + cl;
      int hh = n_g >> 7, rr = n_g & 127;
      float bv = bias[hh * 192 + rr];
      _Float16* dstbase = (rr < 64) ? Qh : Kh;
      int d = rr & 63;
#pragma unroll
      for (int r = 0; r < 4; ++r) {
        int row_g = m0 + wm * 64 + mt * 16 + (l >> 4) * 4 + r;
        int bb = row_g >> 11, lr = row_g & 2047;
        dstbase[(((size_t)bb * NH + hh) * L_SEQ + lr) * DKV + d] = (_Float16)(acc[mt][nt][r] + bv);
      }
    }
  }
}

// ---------------------------------------------------------------------------
// Kernel D (v7): 2-slab pipelined softmax. Block owns slabs A,B (32 q each)
// of one (b,h). Phase1: sums(A). Phase2: stores(A) + sums(B) sharing the same
// staged K tile (stores drain under B's MFMA/exp). Phase3: stores(B).
// K staged via global_load_lds dbuf (XOR-swizzled granules), 128-j steps.
// Normalization folded into exponent via LDS-broadcast cc = -log2(sum).
// ---------------------------------------------------------------------------
__global__ __launch_bounds__(256, 4) void attn_softmax_kernel(const _Float16* __restrict__ Qh,
                                                              const _Float16* __restrict__ Kh,
                                                              float* __restrict__ out) {
  __shared__ _Float16 Ks[2][128 * 64];  // 32 KB dbuf, granule-swizzled rows
  __shared__ float red[4][32];
  __shared__ float ccs[2][32];
  int id = blockIdx.x;
  int xcd = id & 7;
  int rest = id >> 3;
  int pr = rest & 31;
  int bh = ((rest >> 5) << 3) + xcd;  // bijective XCD swizzle
  int t = threadIdx.x;
  int l = t & 63;
  int wv = t >> 6;
  int lj = l & 31;   // 32-lane index (q-col in sum pass / j-col in store pass)
  int hk = l >> 5;   // k-half / row-half
  int qA = pr * 64, qB = pr * 64 + 32;
  const _Float16* Qb = Qh + (size_t)bh * L_SEQ * DKV;
  const _Float16* Kb = Kh + (size_t)bh * L_SEQ * DKV;
  const float SC = 0.18033688011112042f;  // log2(e)/sqrt(64)

  half8v bqA[4], bqB[4];
#pragma unroll
  for (int ks = 0; ks < 4; ++ks) {
    bqA[ks] = *(const half8v*)(Qb + (size_t)(qA + lj) * DKV + ks * 16 + hk * 8);
    bqB[ks] = *(const half8v*)(Qb + (size_t)(qB + lj) * DKV + ks * 16 + hk * 8);
  }
  int krow = wv * 32 + lj;  // this wave's j-strip row within the 128-j tile

#define STAGE(bufi, j0)                                                     \
  {                                                                         \
    _Pragma("unroll") for (int c = 0; c < 4; ++c) {                         \
      int gi = (wv * 4 + c) * 64 + l;                                       \
      int r_ = gi >> 3, s_ = gi & 7;                                        \
      gll16(Kb + (size_t)((j0) + r_) * DKV + 8 * (s_ ^ (r_ & 7)),           \
            &Ks[bufi][(wv * 4 + c) * 512]);                                 \
    }                                                                       \
  }
#define LOADBK(bk, bufi)                                                    \
  _Pragma("unroll") for (int ks = 0; ks < 4; ++ks)                          \
      bk[ks] = *(const half8v*)(&Ks[bufi][krow * 64 + 8 * ((2 * ks + hk) ^ (krow & 7))]);

  int buf = 0;
  STAGE(0, 0);
  __syncthreads();

  // ---- Phase 1: sums(A).  mfma(K,Q): D col = q = lj ----
  float lsum = 0.f;
  for (int s = 0; s < 16; ++s) {
    STAGE(buf ^ 1, ((s + 1) & 15) * 128);  // wrap: last step re-stages tile 0
    half8v bk[4];
    LOADBK(bk, buf);
    float16v acc = {};
#pragma unroll
    for (int ks = 0; ks < 4; ++ks)
      acc = __builtin_amdgcn_mfma_f32_32x32x16_f16(bk[ks], bqA[ks], acc, 0, 0, 0);
#pragma unroll
    for (int i = 0; i < 16; ++i) lsum += __builtin_amdgcn_exp2f(acc[i] * SC);
    __syncthreads();
    buf ^= 1;
  }
  lsum += __shfl_xor(lsum, 32);
  if (l < 32) red[wv][lj] = lsum;
  __syncthreads();
  if (t < 32) ccs[0][t] = -__log2f(red[0][t] + red[1][t] + red[2][t] + red[3][t]);
  __syncthreads();

  // ---- Phase 2: stores(A) + sums(B), shared K tile ----
  size_t orowA = ((size_t)bh * L_SEQ + qA) * L_SEQ;
  lsum = 0.f;
  for (int s = 0; s < 16; ++s) {
    STAGE(buf ^ 1, ((s + 1) & 15) * 128);
    half8v bk[4];
    LOADBK(bk, buf);
    // A stores: mfma(Q,K): D col = j
    float16v acc = {};
#pragma unroll
    for (int ks = 0; ks < 4; ++ks)
      acc = __builtin_amdgcn_mfma_f32_32x32x16_f16(bqA[ks], bk[ks], acc, 0, 0, 0);
    size_t col = (size_t)s * 128 + wv * 32 + lj;
#pragma unroll
    for (int i = 0; i < 16; ++i) {
      int qo = (i & 3) + 8 * (i >> 2) + 4 * hk;
      float p = __builtin_amdgcn_exp2f(acc[i] * SC + ccs[0][qo]);
      __builtin_nontemporal_store(p, out + orowA + (size_t)qo * L_SEQ + col);
    }
    // B sums: mfma(K,Q): D col = q  (stores drain under this)
    float16v acc2 = {};
#pragma unroll
    for (int ks = 0; ks < 4; ++ks)
      acc2 = __builtin_amdgcn_mfma_f32_32x32x16_f16(bk[ks], bqB[ks], acc2, 0, 0, 0);
#pragma unroll
    for (int i = 0; i < 16; ++i) lsum += __builtin_amdgcn_exp2f(acc2[i] * SC);
    __syncthreads();
    buf ^= 1;
  }
  lsum += __shfl_xor(lsum, 32);
  if (l < 32) red[wv][lj] = lsum;
  __syncthreads();
  if (t < 32) ccs[1][t] = -__log2f(red[0][t] + red[1][t] + red[2][t] + red[3][t]);
  __syncthreads();

  // ---- Phase 3: stores(B) ----
  size_t orowB = ((size_t)bh * L_SEQ + qB) * L_SEQ;
  for (int s = 0; s < 16; ++s) {
    if (s + 1 < 16) STAGE(buf ^ 1, (s + 1) * 128);
    half8v bk[4];
    LOADBK(bk, buf);
    float16v acc = {};
#pragma unroll
    for (int ks = 0; ks < 4; ++ks)
      acc = __builtin_amdgcn_mfma_f32_32x32x16_f16(bqB[ks], bk[ks], acc, 0, 0, 0);
    size_t col = (size_t)s * 128 + wv * 32 + lj;
#pragma unroll
    for (int i = 0; i < 16; ++i) {
      int qo = (i & 3) + 8 * (i >> 2) + 4 * hk;
      float p = __builtin_amdgcn_exp2f(acc[i] * SC + ccs[1][qo]);
      __builtin_nontemporal_store(p, out + orowB + (size_t)qo * L_SEQ + col);
    }
    __syncthreads();
    buf ^= 1;
  }
#undef STAGE
#undef LOADBK
}

// ---------------------------------------------------------------------------
extern "C" void kernel_launch(void* const* d_in, const int* in_sizes, int n_in,
                              void* d_out, int out_size, void* d_ws, size_t ws_size,
                              hipStream_t stream) {
  const float* X = (const float*)d_in[0];
  const float* W = (const float*)d_in[1];
  const float* bias = (const float*)d_in[2];
  float* out = (float*)d_out;
  char* ws = (char*)d_ws;
  _Float16* Wt = (_Float16*)ws;                       // 4 MB
  _Float16* Qh = (_Float16*)(ws + (4ull << 20));      // 8 MB
  _Float16* Kh = (_Float16*)(ws + (12ull << 20));     // 8 MB
  _Float16* X16 = (_Float16*)(ws + (20ull << 20));    // 8 MB (total 28 MB)

  xcast_kernel<<<2048, 256, 0, stream>>>(X, X16);
  wpack_kernel<<<dim3(64, 32), 256, 0, stream>>>(W, Wt);
  qk_gemm_kernel<<<dim3(16, 32), 256, 0, stream>>>(X16, Wt, bias, Qh, Kh);
  attn_softmax_kernel<<<1024, 256, 0, stream>>>(Qh, Kh, out);
}